// Round 13
// baseline (152.348 us; speedup 1.0000x reference)
//
#include <hip/hip_runtime.h>
#include <hip/hip_bf16.h>

typedef __attribute__((ext_vector_type(4))) float f32x4;
typedef __attribute__((ext_vector_type(8))) short bf16x8;
typedef __attribute__((ext_vector_type(4))) unsigned int u32x4;

#define BB 4
#define C 256
#define N 4096
#define TS 32
#define EPSI 1e-5f

constexpr size_t BBNC = (size_t)BB * N * C;

__device__ __forceinline__ unsigned short f2bf(float f) {
    unsigned int u = __builtin_bit_cast(unsigned int, f);
    u += 0x7fffu + ((u >> 16) & 1u);
    return (unsigned short)(u >> 16);
}

__device__ __forceinline__ float bf2f(unsigned short h) {
    unsigned int u = ((unsigned int)h) << 16;
    return __builtin_bit_cast(float, u);
}

__device__ __forceinline__ unsigned int cvt_pk_bf16(float lo, float hi) {
    unsigned int r;
    asm("v_cvt_pk_bf16_f32 %0, %1, %2" : "=v"(r) : "v"(lo), "v"(hi));
    return r;
}

// async global->LDS, 16B per lane; LDS dest is uniform-base + linear per-lane offset.
__device__ __forceinline__ void stage16(const unsigned short* g, unsigned short* l) {
    __builtin_amdgcn_global_load_lds(
        (const __attribute__((address_space(1))) void*)g,
        (__attribute__((address_space(3))) void*)l, 16, 0, 0);
}

// ---------------- Kernel 1: BN stats + Wqkv->bf16 + Wout->bf16 ----------------
// Blocks [0,C): BN stats. [C, C+96): Wqkv cvt. [C+96, C+128): Wout cvt.
__global__ __launch_bounds__(256) void bn_stats_k(
    const float* __restrict__ x, const float* __restrict__ gamma,
    const float* __restrict__ beta, float* __restrict__ scale, float* __restrict__ shift,
    const float* __restrict__ Wqkv, unsigned short* __restrict__ wqkv_bf,
    const float* __restrict__ Wout, unsigned short* __restrict__ wout_bf)
{
    int tid = threadIdx.x;
    if (blockIdx.x >= C) {
        int cb = blockIdx.x - C;
        const float* src;
        unsigned short* dst;
        size_t i;
        if (cb < 96) { src = Wqkv; dst = wqkv_bf; i = (size_t)cb * 256 + tid; }
        else         { src = Wout; dst = wout_bf; i = (size_t)(cb - 96) * 256 + tid; }
        const float4* p = (const float4*)(src + i * 8);
        float4 a = p[0], c = p[1];
        unsigned int pk[4];
        pk[0] = cvt_pk_bf16(a.x, a.y);
        pk[1] = cvt_pk_bf16(a.z, a.w);
        pk[2] = cvt_pk_bf16(c.x, c.y);
        pk[3] = cvt_pk_bf16(c.z, c.w);
        *(u32x4*)(dst + i * 8) = *(u32x4*)pk;
        return;
    }
    int c = blockIdx.x;
    float s = 0.f, s2 = 0.f;
    for (int b = 0; b < BB; ++b) {
        const float4* p = (const float4*)(x + ((size_t)b * C + c) * N);
        for (int i = tid; i < N / 4; i += 256) {
            float4 v = p[i];
            s  += v.x + v.y + v.z + v.w;
            s2 += v.x * v.x + v.y * v.y + v.z * v.z + v.w * v.w;
        }
    }
    for (int m = 1; m < 64; m <<= 1) {
        s  += __shfl_xor(s, m);
        s2 += __shfl_xor(s2, m);
    }
    __shared__ float rs[4], rs2[4];
    int w = tid >> 6;
    if ((tid & 63) == 0) { rs[w] = s; rs2[w] = s2; }
    __syncthreads();
    if (tid == 0) {
        float S  = rs[0] + rs[1] + rs[2] + rs[3];
        float S2 = rs2[0] + rs2[1] + rs2[2] + rs2[3];
        const float inv_n = 1.f / (BB * N);
        float mean = S * inv_n;
        float var  = S2 * inv_n - mean * mean;
        float sc = gamma[c] * rsqrtf(var + EPSI);
        scale[c] = sc;
        shift[c] = beta[c] - mean * sc;
    }
}

// ---------------- Kernel 2: fused BN-apply + QKV projection (x read ONCE) ------
__global__ __launch_bounds__(256) void qkv_gemm_k(
    const float* __restrict__ x, const unsigned short* __restrict__ wqkv_bf,
    const float* __restrict__ bqkv,
    const float* __restrict__ scale, const float* __restrict__ shift,
    unsigned short* __restrict__ q, unsigned short* __restrict__ kt, unsigned short* __restrict__ v)
{
    __shared__ unsigned short Alds[32 * 264];   // [t][c], stride 264
    __shared__ unsigned short Wlds[64 * 256];   // [o][c-chunks^], gload_lds + XOR

    int tid = threadIdx.x;
    int b  = blockIdx.y;
    int T0 = blockIdx.x * 32;
    int lane = tid & 63;
    int w = tid >> 6;
    int wm = w >> 1, wn = w & 1;
    int g = lane >> 4, l15 = lane & 15;

    // stage A once: transpose + BN + bf16
    {
        int cbase = tid >> 1;          // 0..127
        int t0 = (tid & 1) * 16;
#pragma unroll
        for (int pass = 0; pass < 2; ++pass) {
            int cc = cbase + pass * 128;
            const float4* xp = (const float4*)(x + ((size_t)b * C + cc) * N + T0 + t0);
            float sc = scale[cc], sh = shift[cc];
#pragma unroll
            for (int j = 0; j < 4; ++j) {
                float4 vv = xp[j];
                int t = t0 + j * 4;
                Alds[(t + 0) * 264 + cc] = f2bf(vv.x * sc + sh);
                Alds[(t + 1) * 264 + cc] = f2bf(vv.y * sc + sh);
                Alds[(t + 2) * 264 + cc] = f2bf(vv.z * sc + sh);
                Alds[(t + 3) * 264 + cc] = f2bf(vv.w * sc + sh);
            }
        }
    }

    const float QSCALE = 0.0625f * 1.44269504088896f;   // (1/sqrt(256)) * log2(e)

    for (int oi = 0; oi < 12; ++oi) {
        int O0 = oi * 64;
        __syncthreads();   // protect Wlds (and, at oi=0, publish Alds)
        {
            const unsigned short* wb = wqkv_bf + (size_t)O0 * 256;
#pragma unroll
            for (int j = 0; j < 8; ++j) {
                int qq = tid + j * 256;
                int lo = qq >> 5, sc2 = qq & 31;
                stage16(wb + (size_t)lo * 256 + ((sc2 ^ (lo & 7)) * 8), &Wlds[qq * 8]);
            }
        }
        __syncthreads();   // drains vmcnt: W tile ready

        f32x4 acc[2];
        acc[0] = f32x4{0.f, 0.f, 0.f, 0.f};
        acc[1] = f32x4{0.f, 0.f, 0.f, 0.f};
#pragma unroll
        for (int kk = 0; kk < 8; ++kk) {
            bf16x8 afr = *(const bf16x8*)&Alds[(wm * 16 + l15) * 264 + kk * 32 + g * 8];
#pragma unroll
            for (int nf = 0; nf < 2; ++nf) {
                int lo = wn * 32 + nf * 16 + l15;
                bf16x8 bfr = *(const bf16x8*)&Wlds[lo * 256 + (((kk * 4 + g) ^ (lo & 7)) * 8)];
                acc[nf] = __builtin_amdgcn_mfma_f32_16x16x32_bf16(afr, bfr, acc[nf], 0, 0, 0);
            }
        }

#pragma unroll
        for (int nf = 0; nf < 2; ++nf) {
            int o = O0 + wn * 32 + nf * 16 + l15;
            float bias = bqkv[o];
#pragma unroll
            for (int r = 0; r < 4; ++r) {
                int t = T0 + wm * 16 + g * 4 + r;
                float val = acc[nf][r] + bias;
                if (O0 < 256) {
                    q[((size_t)b * N + t) * C + o] = f2bf(val * QSCALE);
                } else if (O0 < 512) {
                    kt[((size_t)b * N + t) * C + (o - 256)] = f2bf(val);
                } else {
                    int tp = (t & ~31) | ((g * 2 + wm) * 4 + r);
                    v[((size_t)b * C + (o - 512)) * N + tp] = f2bf(val);
                }
            }
        }
    }
}

// ---------------- Kernel 3: flash attention (PV-lag pipeline, T15 analog) ------
// As R12 (mrep=2, NSEG segs, 2 blocks/CU) but PV(t-1) executes in iter t,
// textually adjacent to softmax(t): the two are INDEPENDENT (PV uses pf from
// t-1; softmax uses fresh st), so MFMA and VALU overlap instead of serializing.
// K(t+1) staged at iter start; V(t+1) staged post-barrier (slot freed by
// PV(t-1)); V(tau) lives in Vlds[tau&1]. Rescale-on-trigger stays after the PV
// block (flash algebra). One __syncthreads per iter, as before.
template<int NSEG>
__global__ __launch_bounds__(256, 2) void attn_k(
    const unsigned short* __restrict__ q, const unsigned short* __restrict__ kt,
    const unsigned short* __restrict__ v,
    unsigned short* __restrict__ P, float* __restrict__ ml)
{
    constexpr int NS  = N / NSEG;    // tokens per segment
    constexpr int NIT = NS / TS;     // tile iterations
    __shared__ unsigned short Klds[2][TS * 256];   // dbuf [tk][c-chunks^] 32KB
    __shared__ unsigned short Vlds[2][256 * TS];   // dbuf [c][tok-slots]  32KB

    int tid = threadIdx.x;
    int h  = blockIdx.y;          // KV segment
    int b  = blockIdx.z;
    int Q0 = blockIdx.x * 128;
    int lane = tid & 63;
    int lw = tid >> 6;            // wave = 32 Q rows
    int g = lane >> 4, l15 = lane & 15;

    bf16x8 qf[2][8];
#pragma unroll
    for (int m = 0; m < 2; ++m) {
        const unsigned short* qp = q + ((size_t)b * N + Q0 + lw * 32 + m * 16 + l15) * C + g * 8;
#pragma unroll
        for (int kc = 0; kc < 8; ++kc)
            qf[m][kc] = *(const bf16x8*)(qp + kc * 32);
    }

    f32x4 oacc[2][16];
#pragma unroll
    for (int m = 0; m < 2; ++m)
#pragma unroll
        for (int i = 0; i < 16; ++i) oacc[m][i] = f32x4{0.f, 0.f, 0.f, 0.f};
    float mrow[2] = {-1e30f, -1e30f};   // common across g (log2 domain)
    float lg[2]   = {0.f, 0.f};         // per-lane partial sum

    const unsigned short* kb = kt + ((size_t)b * N + h * NS) * C;
    const unsigned short* vb = v + (size_t)b * C * N + h * NS;

#define STAGE_K(buf_, t_)                                                            \
    {                                                                                \
        const unsigned short* kbt = kb + (size_t)(t_) * TS * 256;                    \
        _Pragma("unroll")                                                            \
        for (int j = 0; j < 4; ++j) {                                                \
            int qq = tid + j * 256;                                                  \
            int tk = qq >> 5, sc = qq & 31;                                          \
            stage16(kbt + tk * 256 + ((sc ^ (tk & 7)) * 8), &Klds[buf_][qq * 8]);    \
        }                                                                            \
    }
#define STAGE_V(buf_, t_)                                                            \
    {                                                                                \
        _Pragma("unroll")                                                            \
        for (int j = 0; j < 4; ++j) {                                                \
            int qq = tid + j * 256;                                                  \
            int c = qq >> 2, sl = qq & 3;                                            \
            stage16(vb + (size_t)c * N + (t_) * TS + ((sl ^ ((c >> 1) & 3)) * 8),    \
                    &Vlds[buf_][qq * 8]);                                            \
        }                                                                            \
    }

    STAGE_K(0, 0);
    STAGE_V(0, 0);
    __syncthreads();   // tile 0 ready

    bf16x8 pf[2];      // loop-carried P fragment of tile t-1

    for (int t = 0; t < NIT; ++t) {
        int s = t & 1;
        if (t + 1 < NIT) STAGE_K(s ^ 1, t + 1);

        // ---- QK^T(t) from Klds[s] ----
        f32x4 st[2][2];
#pragma unroll
        for (int m = 0; m < 2; ++m)
#pragma unroll
            for (int ct = 0; ct < 2; ++ct) st[m][ct] = f32x4{0.f, 0.f, 0.f, 0.f};
        __builtin_amdgcn_s_setprio(1);
#pragma unroll
        for (int kc = 0; kc < 8; ++kc) {
#pragma unroll
            for (int ct = 0; ct < 2; ++ct) {
                int tk = ct * 16 + l15;
                int slot = (kc * 4 + g) ^ (tk & 7);
                bf16x8 kf = *(const bf16x8*)&Klds[s][tk * 256 + slot * 8];
                st[0][ct] = __builtin_amdgcn_mfma_f32_16x16x32_bf16(kf, qf[0][kc], st[0][ct], 0, 0, 0);
                st[1][ct] = __builtin_amdgcn_mfma_f32_16x16x32_bf16(kf, qf[1][kc], st[1][ct], 0, 0, 0);
            }
        }
        __builtin_amdgcn_s_setprio(0);

        // ---- PV(t-1) from Vlds[s^1], pf (independent of softmax below) ----
        if (t > 0) {
            __builtin_amdgcn_s_setprio(1);
#pragma unroll
            for (int cf = 0; cf < 16; ++cf) {
                int c = cf * 16 + l15;
                int vslot = g ^ ((c >> 1) & 3);
                bf16x8 vf = *(const bf16x8*)&Vlds[s ^ 1][c * TS + vslot * 8];
                oacc[0][cf] = __builtin_amdgcn_mfma_f32_16x16x32_bf16(vf, pf[0], oacc[0][cf], 0, 0, 0);
                oacc[1][cf] = __builtin_amdgcn_mfma_f32_16x16x32_bf16(vf, pf[1], oacc[1][cf], 0, 0, 0);
            }
            __builtin_amdgcn_s_setprio(0);
        }

        // ---- softmax(t): st -> pf (rescale textually after PV block) ----
        float mx[2];
#pragma unroll
        for (int m = 0; m < 2; ++m)
            mx[m] = fmaxf(fmaxf(fmaxf(st[m][0][0], st[m][0][1]), fmaxf(st[m][0][2], st[m][0][3])),
                          fmaxf(fmaxf(st[m][1][0], st[m][1][1]), fmaxf(st[m][1][2], st[m][1][3])));
        bool ok = (mx[0] - mrow[0] <= 8.f) & (mx[1] - mrow[1] <= 8.f);
        if (!__all(ok)) {
#pragma unroll
            for (int m = 0; m < 2; ++m) {
                float v0 = mx[m];
                v0 = fmaxf(v0, __shfl_xor(v0, 16));
                v0 = fmaxf(v0, __shfl_xor(v0, 32));
                float mn = fmaxf(mrow[m], v0);
                float alpha = exp2f(mrow[m] - mn);
                mrow[m] = mn;
                lg[m] *= alpha;
#pragma unroll
                for (int f = 0; f < 16; ++f)
#pragma unroll
                    for (int r = 0; r < 4; ++r) oacc[m][f][r] *= alpha;
            }
        }
#pragma unroll
        for (int m = 0; m < 2; ++m) {
            float rs = 0.f;
#pragma unroll
            for (int ct = 0; ct < 2; ++ct)
#pragma unroll
                for (int r = 0; r < 4; ++r) {
                    float p = exp2f(st[m][ct][r] - mrow[m]);
                    st[m][ct][r] = p;
                    rs += p;
                }
            lg[m] += rs;
            u32x4 pk;
            pk[0] = cvt_pk_bf16(st[m][0][0], st[m][0][1]);
            pk[1] = cvt_pk_bf16(st[m][0][2], st[m][0][3]);
            pk[2] = cvt_pk_bf16(st[m][1][0], st[m][1][1]);
            pk[3] = cvt_pk_bf16(st[m][1][2], st[m][1][3]);
            pf[m] = __builtin_bit_cast(bf16x8, pk);
        }

        __syncthreads();   // drains K(t+1); frees Vlds[s^1] (PV(t-1) done block-wide)
        if (t + 1 < NIT) STAGE_V(s ^ 1, t + 1);
    }

    // ---- epilogue PV(NIT-1) from Vlds[(NIT-1)&1] ----
    {
        int s = (NIT - 1) & 1;
#pragma unroll
        for (int cf = 0; cf < 16; ++cf) {
            int c = cf * 16 + l15;
            int vslot = g ^ ((c >> 1) & 3);
            bf16x8 vf = *(const bf16x8*)&Vlds[s][c * TS + vslot * 8];
            oacc[0][cf] = __builtin_amdgcn_mfma_f32_16x16x32_bf16(vf, pf[0], oacc[0][cf], 0, 0, 0);
            oacc[1][cf] = __builtin_amdgcn_mfma_f32_16x16x32_bf16(vf, pf[1], oacc[1][cf], 0, 0, 0);
        }
    }

    // epilogue: cross-g l-sum (once), then write partials + m,l
    float lt[2];
#pragma unroll
    for (int m = 0; m < 2; ++m) {
        float v0 = lg[m];
        v0 += __shfl_xor(v0, 16);
        v0 += __shfl_xor(v0, 32);
        lt[m] = v0;
    }
#pragma unroll
    for (int m = 0; m < 2; ++m) {
        size_t tokid = (size_t)b * N + Q0 + lw * 32 + m * 16 + l15;
        if (g == 0) {
            ml[(size_t)(2 * h + 0) * (BB * N) + tokid] = mrow[m];
            ml[(size_t)(2 * h + 1) * (BB * N) + tokid] = lt[m];
        }
        unsigned short* pp = P + (size_t)h * BBNC + tokid * C;
#pragma unroll
        for (int cf = 0; cf < 16; ++cf) {
#pragma unroll
            for (int rp = 0; rp < 2; ++rp) {
                int c = cf * 16 + g * 4 + rp * 2;
                unsigned int pk2 = cvt_pk_bf16(oacc[m][cf][rp * 2 + 0], oacc[m][cf][rp * 2 + 1]);
                *(unsigned int*)&pp[c] = pk2;
            }
        }
    }
}

// ---------------- Kernel 4: out projection + combine (P read ONCE) ------------
template<int NSEG>
__global__ __launch_bounds__(256) void out_gemm_k(
    const unsigned short* __restrict__ P, const float* __restrict__ ml,
    const unsigned short* __restrict__ wout_bf, const float* __restrict__ bout,
    const float* __restrict__ x, float* __restrict__ out)
{
    __shared__ unsigned short Alds[256 * 40];   // Wout [co][32c] bf16, pad 40
    __shared__ unsigned short Blds[32 * 40];    // combined ao [t][32c]

    int tid = threadIdx.x;
    int b  = blockIdx.y;
    int T0 = blockIdx.x * 32;
    int lane = tid & 63;
    int w = tid >> 6;
    int g = lane >> 4, l15 = lane & 15;

    int tl = (tid >> 2) & 31;
    float cw[NSEG], cinv;
    {
        size_t tok = (size_t)b * N + T0 + tl;
        float ms[NSEG], ls[NSEG];
#pragma unroll
        for (int s = 0; s < NSEG; ++s) {
            ms[s] = ml[(size_t)(2 * s + 0) * (BB * N) + tok];
            ls[s] = ml[(size_t)(2 * s + 1) * (BB * N) + tok];
        }
        float M = ms[0];
#pragma unroll
        for (int s = 1; s < NSEG; ++s) M = fmaxf(M, ms[s]);
        float den = 0.f;
#pragma unroll
        for (int s = 0; s < NSEG; ++s) {
            cw[s] = exp2f(ms[s] - M);
            den += cw[s] * ls[s];
        }
        cinv = 1.f / den;
    }

    f32x4 acc[4][2];
#pragma unroll
    for (int i = 0; i < 4; ++i)
#pragma unroll
        for (int j = 0; j < 2; ++j) acc[i][j] = f32x4{0.f, 0.f, 0.f, 0.f};

    for (int c0 = 0; c0 < C; c0 += 32) {
        if (c0) __syncthreads();
        {   // stage A: pre-converted bf16 Wout row tid, cols c0..c0+32
            const unsigned short* wp = wout_bf + (size_t)tid * C + c0;
#pragma unroll
            for (int jj = 0; jj < 4; ++jj)
                *(bf16x8*)&Alds[tid * 40 + jj * 8] = *(const bf16x8*)(wp + jj * 8);
        }
        if (tid < 128) {
            int j = tid & 3;
            size_t base = ((size_t)b * N + T0 + tl) * C + c0 + j * 8;
            float val[8];
#pragma unroll
            for (int e = 0; e < 8; ++e) val[e] = 0.f;
#pragma unroll
            for (int s = 0; s < NSEG; ++s) {
                bf16x8 p = *(const bf16x8*)(P + (size_t)s * BBNC + base);
                float wgt = cw[s];
#pragma unroll
                for (int e = 0; e < 8; ++e) val[e] += wgt * bf2f((unsigned short)p[e]);
            }
            unsigned int opk[4];
#pragma unroll
            for (int jj = 0; jj < 4; ++jj)
                opk[jj] = cvt_pk_bf16(val[2 * jj] * cinv, val[2 * jj + 1] * cinv);
            *(u32x4*)&Blds[tl * 40 + j * 8] = *(u32x4*)opk;
        }
        __syncthreads();

        bf16x8 afr[4];
#pragma unroll
        for (int mf = 0; mf < 4; ++mf)
            afr[mf] = *(const bf16x8*)&Alds[(w * 64 + mf * 16 + l15) * 40 + g * 8];
#pragma unroll
        for (int tf = 0; tf < 2; ++tf) {
            bf16x8 bfr = *(const bf16x8*)&Blds[(tf * 16 + l15) * 40 + g * 8];
#pragma unroll
            for (int mf = 0; mf < 4; ++mf)
                acc[mf][tf] = __builtin_amdgcn_mfma_f32_16x16x32_bf16(afr[mf], bfr, acc[mf][tf], 0, 0, 0);
        }
    }

#pragma unroll
    for (int mf = 0; mf < 4; ++mf) {
#pragma unroll
        for (int tf = 0; tf < 2; ++tf) {
            int t = T0 + tf * 16 + l15;
#pragma unroll
            for (int r = 0; r < 4; ++r) {
                int co = w * 64 + mf * 16 + g * 4 + r;
                size_t oidx = ((size_t)b * C + co) * N + t;
                out[oidx] = acc[mf][tf][r] + bout[co] + x[oidx];
            }
        }
    }
}

extern "C" void kernel_launch(void* const* d_in, const int* in_sizes, int n_in,
                              void* d_out, int out_size, void* d_ws, size_t ws_size,
                              hipStream_t stream) {
    const float* x     = (const float*)d_in[0];
    const float* Wqkv  = (const float*)d_in[1];
    const float* bqkv  = (const float*)d_in[2];
    const float* Wout  = (const float*)d_in[3];
    const float* bout  = (const float*)d_in[4];
    const float* gamma = (const float*)d_in[5];
    const float* beta  = (const float*)d_in[6];
    float* out = (float*)d_out;

    char* ws = (char*)d_ws;
    float* scale = (float*)ws;
    float* shift = (float*)(ws + 1024);
    unsigned short* wout_bf = (unsigned short*)(ws + 4096);      // 128KB
    unsigned short* q  = wout_bf + (size_t)C * C;
    unsigned short* kt = q  + BBNC;
    unsigned short* v  = kt + BBNC;
    unsigned short* P  = v  + BBNC;
    // Wqkv-bf16 aliases P: written first, consumed by qkv_gemm, then attn overwrites P.
    unsigned short* wqkv_bf = P;

    size_t need4 = 4096 + (size_t)C * C * 2 + 7 * BBNC * 2 + (size_t)8 * BB * N * 4;

    bn_stats_k<<<dim3(C + 128), dim3(256), 0, stream>>>(x, gamma, beta, scale, shift,
                                                        Wqkv, wqkv_bf, Wout, wout_bf);
    qkv_gemm_k<<<dim3(N / 32, BB), dim3(256), 0, stream>>>(x, wqkv_bf, bqkv, scale, shift, q, kt, v);

    if (ws_size >= need4) {
        float* ml = (float*)(P + 4 * BBNC);
        attn_k<4><<<dim3(N / 128, 4, BB), dim3(256), 0, stream>>>(q, kt, v, P, ml);
        out_gemm_k<4><<<dim3(N / 32, BB), dim3(256), 0, stream>>>(P, ml, wout_bf, bout, x, out);
    } else {
        float* ml = (float*)(P + 2 * BBNC);
        attn_k<2><<<dim3(N / 128, 2, BB), dim3(256), 0, stream>>>(q, kt, v, P, ml);
        out_gemm_k<2><<<dim3(N / 32, BB), dim3(256), 0, stream>>>(P, ml, wout_bf, bout, x, out);
    }
}

// Round 14
// 141.381 us; speedup vs baseline: 1.0776x; 1.0776x over previous
//
#include <hip/hip_runtime.h>
#include <hip/hip_bf16.h>

typedef __attribute__((ext_vector_type(4))) float f32x4;
typedef __attribute__((ext_vector_type(8))) short bf16x8;
typedef __attribute__((ext_vector_type(4))) unsigned int u32x4;

#define BB 4
#define C 256
#define N 4096
#define TS 32
#define EPSI 1e-5f

constexpr size_t BBNC = (size_t)BB * N * C;

__device__ __forceinline__ unsigned short f2bf(float f) {
    unsigned int u = __builtin_bit_cast(unsigned int, f);
    u += 0x7fffu + ((u >> 16) & 1u);
    return (unsigned short)(u >> 16);
}

__device__ __forceinline__ float bf2f(unsigned short h) {
    unsigned int u = ((unsigned int)h) << 16;
    return __builtin_bit_cast(float, u);
}

__device__ __forceinline__ unsigned int cvt_pk_bf16(float lo, float hi) {
    unsigned int r;
    asm("v_cvt_pk_bf16_f32 %0, %1, %2" : "=v"(r) : "v"(lo), "v"(hi));
    return r;
}

// async global->LDS, 16B per lane; LDS dest is uniform-base + linear per-lane offset.
__device__ __forceinline__ void stage16(const unsigned short* g, unsigned short* l) {
    __builtin_amdgcn_global_load_lds(
        (const __attribute__((address_space(1))) void*)g,
        (__attribute__((address_space(3))) void*)l, 16, 0, 0);
}

// ---------------- Kernel 1: BN stats + Wqkv->bf16 + Wout->bf16 ----------------
// Blocks [0,C): BN stats. [C, C+96): Wqkv cvt. [C+96, C+128): Wout cvt.
__global__ __launch_bounds__(256) void bn_stats_k(
    const float* __restrict__ x, const float* __restrict__ gamma,
    const float* __restrict__ beta, float* __restrict__ scale, float* __restrict__ shift,
    const float* __restrict__ Wqkv, unsigned short* __restrict__ wqkv_bf,
    const float* __restrict__ Wout, unsigned short* __restrict__ wout_bf)
{
    int tid = threadIdx.x;
    if (blockIdx.x >= C) {
        int cb = blockIdx.x - C;
        const float* src;
        unsigned short* dst;
        size_t i;
        if (cb < 96) { src = Wqkv; dst = wqkv_bf; i = (size_t)cb * 256 + tid; }
        else         { src = Wout; dst = wout_bf; i = (size_t)(cb - 96) * 256 + tid; }
        const float4* p = (const float4*)(src + i * 8);
        float4 a = p[0], c = p[1];
        unsigned int pk[4];
        pk[0] = cvt_pk_bf16(a.x, a.y);
        pk[1] = cvt_pk_bf16(a.z, a.w);
        pk[2] = cvt_pk_bf16(c.x, c.y);
        pk[3] = cvt_pk_bf16(c.z, c.w);
        *(u32x4*)(dst + i * 8) = *(u32x4*)pk;
        return;
    }
    int c = blockIdx.x;
    float s = 0.f, s2 = 0.f;
    for (int b = 0; b < BB; ++b) {
        const float4* p = (const float4*)(x + ((size_t)b * C + c) * N);
        for (int i = tid; i < N / 4; i += 256) {
            float4 v = p[i];
            s  += v.x + v.y + v.z + v.w;
            s2 += v.x * v.x + v.y * v.y + v.z * v.z + v.w * v.w;
        }
    }
    for (int m = 1; m < 64; m <<= 1) {
        s  += __shfl_xor(s, m);
        s2 += __shfl_xor(s2, m);
    }
    __shared__ float rs[4], rs2[4];
    int w = tid >> 6;
    if ((tid & 63) == 0) { rs[w] = s; rs2[w] = s2; }
    __syncthreads();
    if (tid == 0) {
        float S  = rs[0] + rs[1] + rs[2] + rs[3];
        float S2 = rs2[0] + rs2[1] + rs2[2] + rs2[3];
        const float inv_n = 1.f / (BB * N);
        float mean = S * inv_n;
        float var  = S2 * inv_n - mean * mean;
        float sc = gamma[c] * rsqrtf(var + EPSI);
        scale[c] = sc;
        shift[c] = beta[c] - mean * sc;
    }
}

// ---------------- Kernel 2: fused BN-apply + QKV projection (x read ONCE) ------
__global__ __launch_bounds__(256) void qkv_gemm_k(
    const float* __restrict__ x, const unsigned short* __restrict__ wqkv_bf,
    const float* __restrict__ bqkv,
    const float* __restrict__ scale, const float* __restrict__ shift,
    unsigned short* __restrict__ q, unsigned short* __restrict__ kt, unsigned short* __restrict__ v)
{
    __shared__ unsigned short Alds[32 * 264];   // [t][c], stride 264
    __shared__ unsigned short Wlds[64 * 256];   // [o][c-chunks^], gload_lds + XOR

    int tid = threadIdx.x;
    int b  = blockIdx.y;
    int T0 = blockIdx.x * 32;
    int lane = tid & 63;
    int w = tid >> 6;
    int wm = w >> 1, wn = w & 1;
    int g = lane >> 4, l15 = lane & 15;

    // stage A once: transpose + BN + bf16
    {
        int cbase = tid >> 1;          // 0..127
        int t0 = (tid & 1) * 16;
#pragma unroll
        for (int pass = 0; pass < 2; ++pass) {
            int cc = cbase + pass * 128;
            const float4* xp = (const float4*)(x + ((size_t)b * C + cc) * N + T0 + t0);
            float sc = scale[cc], sh = shift[cc];
#pragma unroll
            for (int j = 0; j < 4; ++j) {
                float4 vv = xp[j];
                int t = t0 + j * 4;
                Alds[(t + 0) * 264 + cc] = f2bf(vv.x * sc + sh);
                Alds[(t + 1) * 264 + cc] = f2bf(vv.y * sc + sh);
                Alds[(t + 2) * 264 + cc] = f2bf(vv.z * sc + sh);
                Alds[(t + 3) * 264 + cc] = f2bf(vv.w * sc + sh);
            }
        }
    }

    const float QSCALE = 0.0625f * 1.44269504088896f;   // (1/sqrt(256)) * log2(e)

    for (int oi = 0; oi < 12; ++oi) {
        int O0 = oi * 64;
        __syncthreads();   // protect Wlds (and, at oi=0, publish Alds)
        {
            const unsigned short* wb = wqkv_bf + (size_t)O0 * 256;
#pragma unroll
            for (int j = 0; j < 8; ++j) {
                int qq = tid + j * 256;
                int lo = qq >> 5, sc2 = qq & 31;
                stage16(wb + (size_t)lo * 256 + ((sc2 ^ (lo & 7)) * 8), &Wlds[qq * 8]);
            }
        }
        __syncthreads();   // drains vmcnt: W tile ready

        f32x4 acc[2];
        acc[0] = f32x4{0.f, 0.f, 0.f, 0.f};
        acc[1] = f32x4{0.f, 0.f, 0.f, 0.f};
#pragma unroll
        for (int kk = 0; kk < 8; ++kk) {
            bf16x8 afr = *(const bf16x8*)&Alds[(wm * 16 + l15) * 264 + kk * 32 + g * 8];
#pragma unroll
            for (int nf = 0; nf < 2; ++nf) {
                int lo = wn * 32 + nf * 16 + l15;
                bf16x8 bfr = *(const bf16x8*)&Wlds[lo * 256 + (((kk * 4 + g) ^ (lo & 7)) * 8)];
                acc[nf] = __builtin_amdgcn_mfma_f32_16x16x32_bf16(afr, bfr, acc[nf], 0, 0, 0);
            }
        }

#pragma unroll
        for (int nf = 0; nf < 2; ++nf) {
            int o = O0 + wn * 32 + nf * 16 + l15;
            float bias = bqkv[o];
#pragma unroll
            for (int r = 0; r < 4; ++r) {
                int t = T0 + wm * 16 + g * 4 + r;
                float val = acc[nf][r] + bias;
                if (O0 < 256) {
                    q[((size_t)b * N + t) * C + o] = f2bf(val * QSCALE);
                } else if (O0 < 512) {
                    kt[((size_t)b * N + t) * C + (o - 256)] = f2bf(val);
                } else {
                    int tp = (t & ~31) | ((g * 2 + wm) * 4 + r);
                    v[((size_t)b * C + (o - 512)) * N + tp] = f2bf(val);
                }
            }
        }
    }
}

// ---------------- Kernel 3: flash attention (R12 schedule, proven 102.6us) -----
// mrep=2, NSEG segs, 2 blocks/CU, shuffle-free steady softmax, in-order
// QK^T -> softmax -> PV with STAGE(K+V of t+1) at iter top, one barrier/iter.
template<int NSEG>
__global__ __launch_bounds__(256, 2) void attn_k(
    const unsigned short* __restrict__ q, const unsigned short* __restrict__ kt,
    const unsigned short* __restrict__ v,
    unsigned short* __restrict__ P, float* __restrict__ ml)
{
    constexpr int NS  = N / NSEG;    // tokens per segment
    constexpr int NIT = NS / TS;     // tile iterations
    __shared__ unsigned short Klds[2][TS * 256];   // dbuf [tk][c-chunks^] 32KB
    __shared__ unsigned short Vlds[2][256 * TS];   // dbuf [c][tok-slots]  32KB

    int tid = threadIdx.x;
    int h  = blockIdx.y;          // KV segment
    int b  = blockIdx.z;
    int Q0 = blockIdx.x * 128;
    int lane = tid & 63;
    int lw = tid >> 6;            // wave = 32 Q rows
    int g = lane >> 4, l15 = lane & 15;

    bf16x8 qf[2][8];
#pragma unroll
    for (int m = 0; m < 2; ++m) {
        const unsigned short* qp = q + ((size_t)b * N + Q0 + lw * 32 + m * 16 + l15) * C + g * 8;
#pragma unroll
        for (int kc = 0; kc < 8; ++kc)
            qf[m][kc] = *(const bf16x8*)(qp + kc * 32);
    }

    f32x4 oacc[2][16];
#pragma unroll
    for (int m = 0; m < 2; ++m)
#pragma unroll
        for (int i = 0; i < 16; ++i) oacc[m][i] = f32x4{0.f, 0.f, 0.f, 0.f};
    float mrow[2] = {-1e30f, -1e30f};   // common across g (log2 domain)
    float lg[2]   = {0.f, 0.f};         // per-lane partial sum (own 8 toks/iter)

    const unsigned short* kb = kt + ((size_t)b * N + h * NS) * C;
    const unsigned short* vb = v + (size_t)b * C * N + h * NS;

#define STAGE(buf_, t_)                                                              \
    {                                                                                \
        const unsigned short* kbt = kb + (size_t)(t_) * TS * 256;                    \
        _Pragma("unroll")                                                            \
        for (int j = 0; j < 4; ++j) {                                                \
            int qq = tid + j * 256;                                                  \
            int tk = qq >> 5, sc = qq & 31;                                          \
            stage16(kbt + tk * 256 + ((sc ^ (tk & 7)) * 8), &Klds[buf_][qq * 8]);    \
        }                                                                            \
        _Pragma("unroll")                                                            \
        for (int j = 0; j < 4; ++j) {                                                \
            int qq = tid + j * 256;                                                  \
            int c = qq >> 2, sl = qq & 3;                                            \
            stage16(vb + (size_t)c * N + (t_) * TS + ((sl ^ ((c >> 1) & 3)) * 8),    \
                    &Vlds[buf_][qq * 8]);                                            \
        }                                                                            \
    }

    STAGE(0, 0);
    __syncthreads();

    for (int t = 0; t < NIT; ++t) {
        int cur = t & 1;
        if (t < NIT - 1) STAGE(cur ^ 1, t + 1);

        f32x4 st[2][2];
#pragma unroll
        for (int m = 0; m < 2; ++m)
#pragma unroll
            for (int ct = 0; ct < 2; ++ct) st[m][ct] = f32x4{0.f, 0.f, 0.f, 0.f};
        __builtin_amdgcn_s_setprio(1);
#pragma unroll
        for (int kc = 0; kc < 8; ++kc) {
#pragma unroll
            for (int ct = 0; ct < 2; ++ct) {
                int tk = ct * 16 + l15;
                int slot = (kc * 4 + g) ^ (tk & 7);
                bf16x8 kf = *(const bf16x8*)&Klds[cur][tk * 256 + slot * 8];
                st[0][ct] = __builtin_amdgcn_mfma_f32_16x16x32_bf16(kf, qf[0][kc], st[0][ct], 0, 0, 0);
                st[1][ct] = __builtin_amdgcn_mfma_f32_16x16x32_bf16(kf, qf[1][kc], st[1][ct], 0, 0, 0);
            }
        }
        __builtin_amdgcn_s_setprio(0);

        // lane-local max over own 8 toks (no shuffles)
        float mx[2];
#pragma unroll
        for (int m = 0; m < 2; ++m)
            mx[m] = fmaxf(fmaxf(fmaxf(st[m][0][0], st[m][0][1]), fmaxf(st[m][0][2], st[m][0][3])),
                          fmaxf(fmaxf(st[m][1][0], st[m][1][1]), fmaxf(st[m][1][2], st[m][1][3])));
        bool ok = (mx[0] - mrow[0] <= 8.f) & (mx[1] - mrow[1] <= 8.f);
        if (!__all(ok)) {
            // rare: establish common max across g, rescale O and lg
#pragma unroll
            for (int m = 0; m < 2; ++m) {
                float v0 = mx[m];
                v0 = fmaxf(v0, __shfl_xor(v0, 16));
                v0 = fmaxf(v0, __shfl_xor(v0, 32));
                float mn = fmaxf(mrow[m], v0);
                float alpha = exp2f(mrow[m] - mn);
                mrow[m] = mn;
                lg[m] *= alpha;
#pragma unroll
                for (int f = 0; f < 16; ++f)
#pragma unroll
                    for (int r = 0; r < 4; ++r) oacc[m][f][r] *= alpha;
            }
        }
        bf16x8 pf[2];
#pragma unroll
        for (int m = 0; m < 2; ++m) {
            float rs = 0.f;
#pragma unroll
            for (int ct = 0; ct < 2; ++ct)
#pragma unroll
                for (int r = 0; r < 4; ++r) {
                    float p = exp2f(st[m][ct][r] - mrow[m]);
                    st[m][ct][r] = p;
                    rs += p;
                }
            lg[m] += rs;   // lane-local; cross-g sum deferred to epilogue
            u32x4 pk;
            pk[0] = cvt_pk_bf16(st[m][0][0], st[m][0][1]);
            pk[1] = cvt_pk_bf16(st[m][0][2], st[m][0][3]);
            pk[2] = cvt_pk_bf16(st[m][1][0], st[m][1][1]);
            pk[3] = cvt_pk_bf16(st[m][1][2], st[m][1][3]);
            pf[m] = __builtin_bit_cast(bf16x8, pk);
        }

        __builtin_amdgcn_s_setprio(1);
#pragma unroll
        for (int cf = 0; cf < 16; ++cf) {
            int c = cf * 16 + l15;
            int vslot = g ^ ((c >> 1) & 3);
            bf16x8 vf = *(const bf16x8*)&Vlds[cur][c * TS + vslot * 8];
            oacc[0][cf] = __builtin_amdgcn_mfma_f32_16x16x32_bf16(vf, pf[0], oacc[0][cf], 0, 0, 0);
            oacc[1][cf] = __builtin_amdgcn_mfma_f32_16x16x32_bf16(vf, pf[1], oacc[1][cf], 0, 0, 0);
        }
        __builtin_amdgcn_s_setprio(0);
        __syncthreads();
    }

    // epilogue: cross-g l-sum (once), then write partials + m,l
    float lt[2];
#pragma unroll
    for (int m = 0; m < 2; ++m) {
        float v0 = lg[m];
        v0 += __shfl_xor(v0, 16);
        v0 += __shfl_xor(v0, 32);
        lt[m] = v0;
    }
#pragma unroll
    for (int m = 0; m < 2; ++m) {
        size_t tokid = (size_t)b * N + Q0 + lw * 32 + m * 16 + l15;
        if (g == 0) {
            ml[(size_t)(2 * h + 0) * (BB * N) + tokid] = mrow[m];
            ml[(size_t)(2 * h + 1) * (BB * N) + tokid] = lt[m];
        }
        unsigned short* pp = P + (size_t)h * BBNC + tokid * C;
#pragma unroll
        for (int cf = 0; cf < 16; ++cf) {
#pragma unroll
            for (int rp = 0; rp < 2; ++rp) {
                int c = cf * 16 + g * 4 + rp * 2;
                unsigned int pk2 = cvt_pk_bf16(oacc[m][cf][rp * 2 + 0], oacc[m][cf][rp * 2 + 1]);
                *(unsigned int*)&pp[c] = pk2;
            }
        }
    }
}

// ---------------- Kernel 4: out projection + combine (P read ONCE) ------------
template<int NSEG>
__global__ __launch_bounds__(256) void out_gemm_k(
    const unsigned short* __restrict__ P, const float* __restrict__ ml,
    const unsigned short* __restrict__ wout_bf, const float* __restrict__ bout,
    const float* __restrict__ x, float* __restrict__ out)
{
    __shared__ unsigned short Alds[256 * 40];   // Wout [co][32c] bf16, pad 40
    __shared__ unsigned short Blds[32 * 40];    // combined ao [t][32c]

    int tid = threadIdx.x;
    int b  = blockIdx.y;
    int T0 = blockIdx.x * 32;
    int lane = tid & 63;
    int w = tid >> 6;
    int g = lane >> 4, l15 = lane & 15;

    int tl = (tid >> 2) & 31;
    float cw[NSEG], cinv;
    {
        size_t tok = (size_t)b * N + T0 + tl;
        float ms[NSEG], ls[NSEG];
#pragma unroll
        for (int s = 0; s < NSEG; ++s) {
            ms[s] = ml[(size_t)(2 * s + 0) * (BB * N) + tok];
            ls[s] = ml[(size_t)(2 * s + 1) * (BB * N) + tok];
        }
        float M = ms[0];
#pragma unroll
        for (int s = 1; s < NSEG; ++s) M = fmaxf(M, ms[s]);
        float den = 0.f;
#pragma unroll
        for (int s = 0; s < NSEG; ++s) {
            cw[s] = exp2f(ms[s] - M);
            den += cw[s] * ls[s];
        }
        cinv = 1.f / den;
    }

    f32x4 acc[4][2];
#pragma unroll
    for (int i = 0; i < 4; ++i)
#pragma unroll
        for (int j = 0; j < 2; ++j) acc[i][j] = f32x4{0.f, 0.f, 0.f, 0.f};

    for (int c0 = 0; c0 < C; c0 += 32) {
        if (c0) __syncthreads();
        {   // stage A: pre-converted bf16 Wout row tid, cols c0..c0+32
            const unsigned short* wp = wout_bf + (size_t)tid * C + c0;
#pragma unroll
            for (int jj = 0; jj < 4; ++jj)
                *(bf16x8*)&Alds[tid * 40 + jj * 8] = *(const bf16x8*)(wp + jj * 8);
        }
        if (tid < 128) {
            int j = tid & 3;
            size_t base = ((size_t)b * N + T0 + tl) * C + c0 + j * 8;
            float val[8];
#pragma unroll
            for (int e = 0; e < 8; ++e) val[e] = 0.f;
#pragma unroll
            for (int s = 0; s < NSEG; ++s) {
                bf16x8 p = *(const bf16x8*)(P + (size_t)s * BBNC + base);
                float wgt = cw[s];
#pragma unroll
                for (int e = 0; e < 8; ++e) val[e] += wgt * bf2f((unsigned short)p[e]);
            }
            unsigned int opk[4];
#pragma unroll
            for (int jj = 0; jj < 4; ++jj)
                opk[jj] = cvt_pk_bf16(val[2 * jj] * cinv, val[2 * jj + 1] * cinv);
            *(u32x4*)&Blds[tl * 40 + j * 8] = *(u32x4*)opk;
        }
        __syncthreads();

        bf16x8 afr[4];
#pragma unroll
        for (int mf = 0; mf < 4; ++mf)
            afr[mf] = *(const bf16x8*)&Alds[(w * 64 + mf * 16 + l15) * 40 + g * 8];
#pragma unroll
        for (int tf = 0; tf < 2; ++tf) {
            bf16x8 bfr = *(const bf16x8*)&Blds[(tf * 16 + l15) * 40 + g * 8];
#pragma unroll
            for (int mf = 0; mf < 4; ++mf)
                acc[mf][tf] = __builtin_amdgcn_mfma_f32_16x16x32_bf16(afr[mf], bfr, acc[mf][tf], 0, 0, 0);
        }
    }

#pragma unroll
    for (int mf = 0; mf < 4; ++mf) {
#pragma unroll
        for (int tf = 0; tf < 2; ++tf) {
            int t = T0 + tf * 16 + l15;
#pragma unroll
            for (int r = 0; r < 4; ++r) {
                int co = w * 64 + mf * 16 + g * 4 + r;
                size_t oidx = ((size_t)b * C + co) * N + t;
                out[oidx] = acc[mf][tf][r] + bout[co] + x[oidx];
            }
        }
    }
}

extern "C" void kernel_launch(void* const* d_in, const int* in_sizes, int n_in,
                              void* d_out, int out_size, void* d_ws, size_t ws_size,
                              hipStream_t stream) {
    const float* x     = (const float*)d_in[0];
    const float* Wqkv  = (const float*)d_in[1];
    const float* bqkv  = (const float*)d_in[2];
    const float* Wout  = (const float*)d_in[3];
    const float* bout  = (const float*)d_in[4];
    const float* gamma = (const float*)d_in[5];
    const float* beta  = (const float*)d_in[6];
    float* out = (float*)d_out;

    char* ws = (char*)d_ws;
    float* scale = (float*)ws;
    float* shift = (float*)(ws + 1024);
    unsigned short* wout_bf = (unsigned short*)(ws + 4096);      // 128KB
    unsigned short* q  = wout_bf + (size_t)C * C;
    unsigned short* kt = q  + BBNC;
    unsigned short* v  = kt + BBNC;
    unsigned short* P  = v  + BBNC;
    // Wqkv-bf16 aliases P: written first, consumed by qkv_gemm, then attn overwrites P.
    unsigned short* wqkv_bf = P;

    size_t need4 = 4096 + (size_t)C * C * 2 + 7 * BBNC * 2 + (size_t)8 * BB * N * 4;

    bn_stats_k<<<dim3(C + 128), dim3(256), 0, stream>>>(x, gamma, beta, scale, shift,
                                                        Wqkv, wqkv_bf, Wout, wout_bf);
    qkv_gemm_k<<<dim3(N / 32, BB), dim3(256), 0, stream>>>(x, wqkv_bf, bqkv, scale, shift, q, kt, v);

    if (ws_size >= need4) {
        float* ml = (float*)(P + 4 * BBNC);
        attn_k<4><<<dim3(N / 128, 4, BB), dim3(256), 0, stream>>>(q, kt, v, P, ml);
        out_gemm_k<4><<<dim3(N / 32, BB), dim3(256), 0, stream>>>(P, ml, wout_bf, bout, x, out);
    } else {
        float* ml = (float*)(P + 2 * BBNC);
        attn_k<2><<<dim3(N / 128, 2, BB), dim3(256), 0, stream>>>(q, kt, v, P, ml);
        out_gemm_k<2><<<dim3(N / 32, BB), dim3(256), 0, stream>>>(P, ml, wout_bf, bout, x, out);
    }
}